// Round 12
// baseline (2421.172 us; speedup 1.0000x reference)
//
#include <hip/hip_runtime.h>
#include <hip/hip_bf16.h>

typedef __attribute__((ext_vector_type(8))) short bf16x8;
typedef __attribute__((ext_vector_type(4))) float f32x4;

constexpr int NB = 64, NS = 512, ND = 512, NH = 1024;
constexpr int G4H = 4096;
constexpr int NWG = 256, NTHR = 512;
constexpr int PS  = 20;            // part[] row stride (floats)

__device__ inline unsigned short f2bf(float f) {
  union { float f; unsigned u; } v; v.f = f;
  unsigned r = v.u + 0x7FFFu + ((v.u >> 16) & 1u);  // RNE
  return (unsigned short)(r >> 16);
}
__device__ inline float sigmoidf_fast(float x) { return 1.0f / (1.0f + __expf(-x)); }
__device__ inline float tanhf_fast(float x) {
  float e = __expf(2.0f * x);
  return 1.0f - 2.0f / (e + 1.0f);
}

// ---------------- prep: x -> bf16, zero flags ----------------
__global__ void prep_kernel(const float* __restrict__ x,
                            unsigned short* __restrict__ xbf,
                            unsigned int* __restrict__ flags) {
  const int idx = blockIdx.x * blockDim.x + threadIdx.x;
  const int nthr = gridDim.x * blockDim.x;
  for (int i = idx; i < NWG * 16; i += nthr) flags[i] = 0u;
  const float4* x4 = (const float4*)x;
  ushort4* xo = (ushort4*)xbf;
  const int n4 = NB * NS * ND / 4;
  for (int i = idx; i < n4; i += nthr) {
    float4 v = x4[i];
    ushort4 o;
    o.x = f2bf(v.x); o.y = f2bf(v.y); o.z = f2bf(v.z); o.w = f2bf(v.w);
    xo[i] = o;
  }
}

// ---------------- main persistent kernel ----------------
// 8 waves = 8 K-eighths (ksteps w, w+8, ..., w+40), each wave computes all 4
// gates for its K slice. h A-frags load DIRECTLY from LLC into MFMA operand
// registers (fragment layout == 16 rows x 64B/row: fully coalesced) — no LDS
// staging, no P4 barrier. x A-frags preload into registers during the poll
// window (normal cached loads; xbf is L3-resident, read-only).
__global__ __launch_bounds__(NTHR, 2)
void lstm_kernel(const float* __restrict__ Wih,
                 const float* __restrict__ Whh,
                 const float* __restrict__ bias,
                 const unsigned short* __restrict__ xbf,
                 unsigned short* __restrict__ hbuf,   // 2 ping-pong NB*NH bf16 (LLC)
                 unsigned int* __restrict__ flags,
                 float* __restrict__ out)
{
  const int tid  = threadIdx.x;
  const int wg   = blockIdx.x;
  const int wave = tid >> 6;
  const int lane = tid & 63;
  const int bb   = wg >> 6;       // batch block (hb-major: XCD-chunk locality)
  const int hb   = wg & 63;       // hidden block (16 cols)

  __shared__ float part[32][16 * PS];   // [wave*4+gate] partial 16x16 tiles (40KB)
  __shared__ float c_state[256];

  if (tid < 256) c_state[tid] = 0.0f;

  // ---------- one-time weight B-frag gather (col = lane&15, k = kbase+(lane>>4)*8+j) ----
  const int kg0  = (lane >> 4) << 3;
  const int colb = (hb << 4) + (lane & 15);
  bf16x8 bfr[4][6];
#pragma unroll
  for (int g = 0; g < 4; ++g) {
    const int col = (g << 10) + colb;
#pragma unroll
    for (int s = 0; s < 6; ++s) {
      const int k0 = (wave + 8 * s) * 32 + kg0;
#pragma unroll
      for (int j = 0; j < 8; ++j) {
        const int k = k0 + j;
        const float wv = (k < ND) ? Wih[(size_t)k * G4H + col]
                                  : Whh[(size_t)(k - ND) * G4H + col];
        bfr[g][s][j] = (short)f2bf(wv);
      }
    }
  }

  const int arow = bb * 16 + (lane & 15);            // absolute batch row (A-frag row)
  const unsigned short* xlane = xbf + (size_t)arow * (NS * ND) + kg0;
  float* ht_out = out + (size_t)NB * NS * NH;
  float* ct_out = ht_out + NB * NH;

  // preload x A-frags for t=0 (ksteps wave, wave+8)
  bf16x8 xf[2];
#pragma unroll
  for (int s = 0; s < 2; ++s)
    xf[s] = *(const bf16x8*)(xlane + (wave + 8 * s) * 32);

  __syncthreads();  // c_state ready

  for (int t = 0; t < NS; ++t) {
    // ---- P1: h A-frag sc1 loads, straight into MFMA operand layout ----
    bf16x8 hf[4];
    if (t > 0) {
      const unsigned short* hrow = hbuf + (size_t)(t & 1) * (NB * NH)
                                        + (size_t)arow * NH + kg0;
#pragma unroll
      for (int s = 0; s < 4; ++s) {
        const int kk = (wave + 8 * (s + 2)) * 32 - 512;  // h-col base of kstep
        const unsigned long long* p = (const unsigned long long*)(hrow + kk);
        unsigned long long lo = __hip_atomic_load(p,     __ATOMIC_RELAXED, __HIP_MEMORY_SCOPE_AGENT);
        unsigned long long hi = __hip_atomic_load(p + 1, __ATOMIC_RELAXED, __HIP_MEMORY_SCOPE_AGENT);
        union { unsigned long long q[2]; bf16x8 v; } u;
        u.q[0] = lo; u.q[1] = hi;
        hf[s] = u.v;
      }
    } else {
#pragma unroll
      for (int s = 0; s < 4; ++s) hf[s] = bf16x8{0,0,0,0,0,0,0,0};
    }

    // ---- P2: x MFMAs (register frags — no LDS, hides h-load latency) ----
    f32x4 acc[4] = {{0,0,0,0},{0,0,0,0},{0,0,0,0},{0,0,0,0}};
#pragma unroll
    for (int s = 0; s < 2; ++s)
#pragma unroll
      for (int g = 0; g < 4; ++g)
        acc[g] = __builtin_amdgcn_mfma_f32_16x16x32_bf16(xf[s], bfr[g][s], acc[g], 0, 0, 0);

    // ---- P5: h MFMAs (operands arrive from LLC; compiler inserts vmcnt) ----
#pragma unroll
    for (int s = 0; s < 4; ++s)
#pragma unroll
      for (int g = 0; g < 4; ++g)
        acc[g] = __builtin_amdgcn_mfma_f32_16x16x32_bf16(hf[s], bfr[g][s + 2], acc[g], 0, 0, 0);

    // ---- P6: partial tiles (C/D: col = lane&15, row = (lane>>4)*4 + reg) ----
    {
      const int r0 = (lane >> 4) << 2;
      const int cc = lane & 15;
#pragma unroll
      for (int g = 0; g < 4; ++g)
#pragma unroll
        for (int j = 0; j < 4; ++j)
          part[wave * 4 + g][(r0 + j) * PS + cc] = acc[g][j];
    }
    __syncthreads();  // B1: parts ready

    // ---- P7: epilogue (waves 0-3): gates, state, h sc1 store + out store ----
    if (tid < 256) {
      const int ec = tid & 15;
      const int er = tid >> 4;
      float pre[4];
#pragma unroll
      for (int go = 0; go < 4; ++go) {
        float s = bias[(go << 10) + (hb << 4) + ec];
#pragma unroll
        for (int w8 = 0; w8 < 8; ++w8)
          s += part[w8 * 4 + go][er * PS + ec];
        pre[go] = s;
      }
      const float it = sigmoidf_fast(pre[0]);
      const float ft = sigmoidf_fast(pre[1]);
      const float gt = tanhf_fast(pre[2]);
      const float ot = sigmoidf_fast(pre[3]);
      const float cn = ft * c_state[tid] + it * gt;
      c_state[tid] = cn;
      const float hn = ot * tanhf_fast(cn);
      const int row  = bb * 16 + er;
      const int hcol = (hb << 4) + ec;
      const size_t ooff = (size_t)row * (NS * NH) + (size_t)t * NH + hcol;
      if (t == NS - 1) {
        out[ooff] = hn;
        ht_out[row * NH + hcol] = hn;
        ct_out[row * NH + hcol] = cn;
      } else {
        unsigned int my = (unsigned int)f2bf(hn);
        unsigned int pa = (unsigned int)__shfl_xor((int)my, 1, 64);
        if ((tid & 1) == 0) {
          unsigned int* p = (unsigned int*)(hbuf + (size_t)((t + 1) & 1) * (NB * NH)
                                                 + (size_t)row * NH + hcol);
          __hip_atomic_store(p, my | (pa << 16), __ATOMIC_RELAXED, __HIP_MEMORY_SCOPE_AGENT);
        }
        __builtin_nontemporal_store(hn, &out[ooff]);
      }
    }

    if (t < NS - 1) {
      // B2: drain epilogue waves' sc1 stores, then make them WG-visible
      if (wave < 4) asm volatile("s_waitcnt vmcnt(0)" ::: "memory");
      __syncthreads();

      // x A-frag preload for t+1 (normal cached loads; retire during poll)
      {
        const unsigned short* xn = xlane + (size_t)(t + 1) * ND;
#pragma unroll
        for (int s = 0; s < 2; ++s)
          xf[s] = *(const bf16x8*)(xn + (wave + 8 * s) * 32);
      }

      // flag + poll (verbatim r7): wave 7 lane 0 posts, wave 7 polls bb-group
      if (tid == (7 << 6))
        __hip_atomic_store(flags + (size_t)wg * 16, (unsigned int)(t + 1),
                           __ATOMIC_RELAXED, __HIP_MEMORY_SCOPE_AGENT);
      if (wave == 7) {
        const unsigned int target = (unsigned int)(t + 1);
        const unsigned int* fp = flags + (size_t)((bb << 6) | lane) * 16;
        while (true) {
          unsigned int fv = __hip_atomic_load(fp, __ATOMIC_RELAXED, __HIP_MEMORY_SCOPE_AGENT);
          if (__all((int)(fv >= target))) break;
          __builtin_amdgcn_s_sleep(1);
        }
      }
      __syncthreads();  // B3: release into step t+1
    }
  }
}

extern "C" void kernel_launch(void* const* d_in, const int* in_sizes, int n_in,
                              void* d_out, int out_size, void* d_ws, size_t ws_size,
                              hipStream_t stream) {
  const float* x    = (const float*)d_in[0];
  const float* wih  = (const float*)d_in[1];
  const float* whh  = (const float*)d_in[2];
  const float* bias = (const float*)d_in[3];
  float* out = (float*)d_out;

  // ws layout: [flags 16KB][hbuf 2*NB*NH bf16 = 256KB][xbf NB*NS*ND bf16 = 32MB]
  unsigned int*   flags = (unsigned int*)d_ws;
  unsigned short* hbuf  = (unsigned short*)((char*)d_ws + 16384);
  unsigned short* xbf   = (unsigned short*)((char*)d_ws + 16384 + (size_t)2 * NB * NH * 2);

  prep_kernel<<<1024, 256, 0, stream>>>(x, xbf, flags);

  void* args[] = { (void*)&wih, (void*)&whh, (void*)&bias,
                   (void*)&xbf, (void*)&hbuf, (void*)&flags, (void*)&out };
  hipLaunchCooperativeKernel((const void*)lstm_kernel, dim3(NWG), dim3(NTHR),
                             args, 0, stream);
}

// Round 13
// 2318.254 us; speedup vs baseline: 1.0444x; 1.0444x over previous
//
#include <hip/hip_runtime.h>
#include <hip/hip_bf16.h>

typedef __attribute__((ext_vector_type(8))) short bf16x8;
typedef __attribute__((ext_vector_type(4))) float f32x4;

constexpr int NB = 64, NS = 512, ND = 512, NH = 1024;
constexpr int G4H = 4096;
constexpr int NWG = 256, NTHR = 512;
constexpr int PS  = 20;            // part[] row stride (floats)
constexpr int TRB = 3072;          // tile row stride bytes

__device__ inline unsigned short f2bf(float f) {
  union { float f; unsigned u; } v; v.f = f;
  unsigned r = v.u + 0x7FFFu + ((v.u >> 16) & 1u);  // RNE
  return (unsigned short)(r >> 16);
}
__device__ inline float sigmoidf_fast(float x) { return 1.0f / (1.0f + __expf(-x)); }
__device__ inline float tanhf_fast(float x) {
  float e = __expf(2.0f * x);
  return 1.0f - 2.0f / (e + 1.0f);
}
// XOR-swizzle intra-row byte offset (involution, applied on write AND read)
__device__ inline int swz(int row, int off) { return row * TRB + (off ^ ((row & 7) << 4)); }

// ---------------- prep: x -> bf16, zero flags ----------------
__global__ void prep_kernel(const float* __restrict__ x,
                            unsigned short* __restrict__ xbf,
                            unsigned int* __restrict__ flags) {
  const int idx = blockIdx.x * blockDim.x + threadIdx.x;
  const int nthr = gridDim.x * blockDim.x;
  for (int i = idx; i < NWG * 16; i += nthr) flags[i] = 0u;
  const float4* x4 = (const float4*)x;
  ushort4* xo = (ushort4*)xbf;
  const int n4 = NB * NS * ND / 4;
  for (int i = idx; i < n4; i += nthr) {
    float4 v = x4[i];
    ushort4 o;
    o.x = f2bf(v.x); o.y = f2bf(v.y); o.z = f2bf(v.z); o.w = f2bf(v.w);
    xo[i] = o;
  }
}

// ---------------- main persistent kernel ----------------
// Dual-sequence interleave: batch = 8 slices of 8 rows; group g (64 WGs)
// owns slices {g, g+4}, alternating phases A(t),B(t),A(t+1),...  While one
// sequence's h propagates through LLC (store->flag->poll->load), the WG
// computes the other sequence — the exchange chain is fully hidden.
// Tile rows 0-7 = active slice; rows 8-15 stay zero (MFMA padding).
__global__ __launch_bounds__(NTHR)
void lstm_kernel(const float* __restrict__ Wih,
                 const float* __restrict__ Whh,
                 const float* __restrict__ bias,
                 const unsigned short* __restrict__ xbf,
                 unsigned short* __restrict__ hbuf,   // [seq8][pp2][8][1024] bf16 (LLC)
                 unsigned int* __restrict__ flags,    // 2 per WG (waves 0,1), 64B apart per WG
                 float* __restrict__ out)
{
  const int tid  = threadIdx.x;
  const int wg   = blockIdx.x;
  const int wave = tid >> 6;
  const int lane = tid & 63;
  const int g    = wg >> 6;       // group: slices {g, g+4}
  const int hb   = wg & 63;       // hidden block (16 cols)
  const int gp   = wave & 1;      // gate pair
  const int q    = wave >> 1;     // K quarter

  __shared__ unsigned short tile[16 * 1536];  // [16][512 x | 1024 h] bf16, swizzled
  __shared__ float part[16][16 * PS];
  __shared__ float c_state[2][128];           // per-sequence cell state

  if (tid < 256) ((float*)c_state)[tid] = 0.0f;

  // ---------- one-time weight B-frag gather (r7 verbatim) ----------
  const int kg0  = (lane >> 4) << 3;
  const int colb = (hb << 4) + (lane & 15);
  bf16x8 wx[2][4], wh[2][8];
#pragma unroll
  for (int gg = 0; gg < 2; ++gg) {
    const int col = ((gp * 2 + gg) << 10) + colb;
#pragma unroll
    for (int s = 0; s < 4; ++s) {
      const int k0 = (q * 4 + s) * 32 + kg0;
#pragma unroll
      for (int j = 0; j < 8; ++j)
        wx[gg][s][j] = (short)f2bf(Wih[(size_t)(k0 + j) * G4H + col]);
    }
#pragma unroll
    for (int u = 0; u < 8; ++u) {
      const int k0 = (q * 8 + u) * 32 + kg0;
#pragma unroll
      for (int j = 0; j < 8; ++j)
        wh[gg][u][j] = (short)f2bf(Whh[(size_t)(k0 + j) * G4H + col]);
    }
  }

  // ---------- prologue: zero whole tile, stage x(seq g, t=0) rows 0-7 ----------
  for (int c = tid; c < 3072; c += NTHR)
    *(uint4*)((char*)tile + c * 16) = uint4{0, 0, 0, 0};
  __syncthreads();
  {
    const int row = tid >> 6, sl = tid & 63;   // 512 slots, one per thread
    const unsigned short* src = xbf + (size_t)(g * 8 + row) * (NS * ND) + sl * 8;
    *(uint4*)((char*)tile + swz(row, sl * 16)) = *(const uint4*)src;
  }
  __syncthreads();

  const int arow = lane & 15;
  float* ht_out = out + (size_t)NB * NS * NH;
  float* ct_out = ht_out + NB * NH;

  for (int p = 0; p < 2 * NS; ++p) {
    const int sq = (p & 1) ? g + 4 : g;   // active slice
    const int t  = p >> 1;

    // ---- MFMA over full K (tile fully pre-staged: zero waits) ----
    f32x4 a0 = {0.f, 0.f, 0.f, 0.f}, a1 = {0.f, 0.f, 0.f, 0.f};
#pragma unroll
    for (int s = 0; s < 4; ++s) {
      const int off = ((q * 4 + s) * 32 + kg0) * 2;
      bf16x8 af = *(const bf16x8*)((const char*)tile + swz(arow, off));
      a0 = __builtin_amdgcn_mfma_f32_16x16x32_bf16(af, wx[0][s], a0, 0, 0, 0);
      a1 = __builtin_amdgcn_mfma_f32_16x16x32_bf16(af, wx[1][s], a1, 0, 0, 0);
    }
#pragma unroll
    for (int u = 0; u < 8; ++u) {
      const int off = 1024 + ((q * 8 + u) * 32 + kg0) * 2;
      bf16x8 af = *(const bf16x8*)((const char*)tile + swz(arow, off));
      a0 = __builtin_amdgcn_mfma_f32_16x16x32_bf16(af, wh[0][u], a0, 0, 0, 0);
      a1 = __builtin_amdgcn_mfma_f32_16x16x32_bf16(af, wh[1][u], a1, 0, 0, 0);
    }

    // ---- partial tiles (rows 8-15 garbage, ignored) ----
    {
      const int r0 = (lane >> 4) << 2;
      const int cc = lane & 15;
#pragma unroll
      for (int j = 0; j < 4; ++j) {
        part[wave * 2 + 0][(r0 + j) * PS + cc] = a0[j];
        part[wave * 2 + 1][(r0 + j) * PS + cc] = a1[j];
      }
    }
    __syncthreads();  // B1

    // ---- epilogue: waves 0-1 (128 threads = 8 rows x 16 cols) ----
    // In parallel: waves 2-6 stage x(next phase); wave 7 polls.
    if (tid < 128) {
      const int ec = tid & 15;
      const int er = tid >> 4;
      float pre[4];
#pragma unroll
      for (int go = 0; go < 4; ++go) {
        float s = bias[(go << 10) + (hb << 4) + ec];
#pragma unroll
        for (int qq = 0; qq < 4; ++qq)
          s += part[(qq * 2 + (go >> 1)) * 2 + (go & 1)][er * PS + ec];
        pre[go] = s;
      }
      const float it = sigmoidf_fast(pre[0]);
      const float ft = sigmoidf_fast(pre[1]);
      const float gt = tanhf_fast(pre[2]);
      const float ot = sigmoidf_fast(pre[3]);
      const float cn = ft * c_state[p & 1][tid] + it * gt;
      c_state[p & 1][tid] = cn;
      const float hn = ot * tanhf_fast(cn);
      const int row  = sq * 8 + er;
      const int hcol = (hb << 4) + ec;
      const size_t ooff = (size_t)row * (NS * NH) + (size_t)t * NH + hcol;
      if (t == NS - 1) {
        out[ooff] = hn;
        ht_out[row * NH + hcol] = hn;
        ct_out[row * NH + hcol] = cn;
      } else {
        // h sc1 store -> drain (own stores only) -> per-wave flag -> out store
        unsigned int my = (unsigned int)f2bf(hn);
        unsigned int pa = (unsigned int)__shfl_xor((int)my, 1, 64);
        if ((tid & 1) == 0) {
          unsigned int* hp = (unsigned int*)(hbuf
              + (size_t)((sq * 2 + (t & 1)) * 8 + er) * 1024 + hcol);
          __hip_atomic_store(hp, my | (pa << 16), __ATOMIC_RELAXED, __HIP_MEMORY_SCOPE_AGENT);
        }
        asm volatile("s_waitcnt vmcnt(0)" ::: "memory");
        if (lane == 0)
          __hip_atomic_store(flags + (size_t)wg * 16 + wave, (unsigned int)(p + 1),
                             __ATOMIC_RELAXED, __HIP_MEMORY_SCOPE_AGENT);
        __builtin_nontemporal_store(hn, &out[ooff]);
      }
    }

    if (p + 1 < 2 * NS) {
      const int sq2 = (p & 1) ? g : g + 4;   // next phase's slice
      const int t2  = (p + 1) >> 1;

      if (wave >= 2 && wave < 7) {
        // x(next phase): 512 slots over 320 threads
        for (int c = tid - 128; c < 512; c += 320) {
          const int row = c >> 6, sl = c & 63;
          const unsigned short* src = xbf + (size_t)(sq2 * 8 + row) * (NS * ND)
                                          + (size_t)t2 * ND + sl * 8;
          *(uint4*)((char*)tile + swz(row, sl * 16)) = *(const uint4*)src;
        }
      }
      if (wave == 7 && p > 0) {
        // poll: stores of phase p-1 (flag value p), posted a full phase ago
        const unsigned int target = (unsigned int)p;
        const unsigned long long* fp =
            (const unsigned long long*)(flags + (size_t)((g << 6) | lane) * 16);
        while (true) {
          unsigned long long v = __hip_atomic_load(fp, __ATOMIC_RELAXED, __HIP_MEMORY_SCOPE_AGENT);
          bool ok = ((unsigned int)v >= target) && ((unsigned int)(v >> 32) >= target);
          if (__all((int)ok)) break;
        }
      }
      __syncthreads();  // B2: poll confirmed, tile x staged, MFMA reads long done

      if (p > 0) {
        // h(next phase) staging: 1024 slots of 16B, 2 per thread (dense sc1 loads)
        const unsigned short* hb2 = hbuf + (size_t)((sq2 * 2 + ((t2 - 1) & 1)) * 8) * 1024;
#pragma unroll
        for (int i = 0; i < 2; ++i) {
          const int c = (tid << 1) | i;
          const int row = c >> 7, sl = c & 127;
          const unsigned long long* pp = (const unsigned long long*)(hb2 + row * 1024 + sl * 8);
          unsigned long long lo = __hip_atomic_load(pp,     __ATOMIC_RELAXED, __HIP_MEMORY_SCOPE_AGENT);
          unsigned long long hi = __hip_atomic_load(pp + 1, __ATOMIC_RELAXED, __HIP_MEMORY_SCOPE_AGENT);
          uint4 v;
          v.x = (unsigned int)lo;
          v.y = (unsigned int)(lo >> 32);
          v.z = (unsigned int)hi;
          v.w = (unsigned int)(hi >> 32);
          *(uint4*)((char*)tile + swz(row, 1024 + sl * 16)) = v;
        }
      }
      __syncthreads();  // B3: release into next phase
    }
  }
}

extern "C" void kernel_launch(void* const* d_in, const int* in_sizes, int n_in,
                              void* d_out, int out_size, void* d_ws, size_t ws_size,
                              hipStream_t stream) {
  const float* x    = (const float*)d_in[0];
  const float* wih  = (const float*)d_in[1];
  const float* whh  = (const float*)d_in[2];
  const float* bias = (const float*)d_in[3];
  float* out = (float*)d_out;

  // ws layout: [flags 16KB][hbuf 8*2*8*1024 bf16 = 256KB][xbf 32MB]
  unsigned int*   flags = (unsigned int*)d_ws;
  unsigned short* hbuf  = (unsigned short*)((char*)d_ws + 16384);
  unsigned short* xbf   = (unsigned short*)((char*)d_ws + 16384 + 262144);

  prep_kernel<<<1024, 256, 0, stream>>>(x, xbf, flags);

  void* args[] = { (void*)&wih, (void*)&whh, (void*)&bias,
                   (void*)&xbf, (void*)&hbuf, (void*)&flags, (void*)&out };
  hipLaunchCooperativeKernel((const void*)lstm_kernel, dim3(NWG), dim3(NTHR),
                             args, 0, stream);
}

// Round 15
// 1358.495 us; speedup vs baseline: 1.7822x; 1.7065x over previous
//
#include <hip/hip_runtime.h>
#include <hip/hip_bf16.h>

typedef __attribute__((ext_vector_type(8))) short bf16x8;
typedef __attribute__((ext_vector_type(4))) float f32x4;

constexpr int NB = 64, NS = 512, ND = 512, NH = 1024;
constexpr int G4H = 4096;
constexpr int NWG = 256, NTHR = 512;
constexpr int PS  = 20;            // part[] row stride (floats)
constexpr int TRB = 3072;          // tile row stride bytes (512*2 + 1024*2)

__device__ inline unsigned short f2bf(float f) {
  union { float f; unsigned u; } v; v.f = f;
  unsigned r = v.u + 0x7FFFu + ((v.u >> 16) & 1u);  // RNE
  return (unsigned short)(r >> 16);
}
__device__ inline float sigmoidf_fast(float x) { return 1.0f / (1.0f + __expf(-x)); }
__device__ inline float tanhf_fast(float x) {
  float e = __expf(2.0f * x);
  return 1.0f - 2.0f / (e + 1.0f);
}
// XOR-swizzle intra-row byte offset (involution, applied on write AND read)
__device__ inline int swz(int row, int off) { return row * TRB + (off ^ ((row & 7) << 4)); }

// ---------------- prep: x -> bf16, init tagged h ping-pong ----------------
// hbuf[0] = 0x0000... : zeros, tag0-valid (= h(0) for t=0 readers)
// hbuf[1] = 0x00010001: tag1 pattern, INVALID for the first (tag0) use
__global__ void prep_kernel(const float* __restrict__ x,
                            unsigned short* __restrict__ xbf,
                            unsigned short* __restrict__ hbuf) {
  const int idx = blockIdx.x * blockDim.x + threadIdx.x;
  const int nthr = gridDim.x * blockDim.x;
  const int nh4 = NB * NH * 2 / 16;          // uint4 chunks per buffer
  uint4* h4 = (uint4*)hbuf;
  for (int i = idx; i < nh4; i += nthr) h4[i] = uint4{0, 0, 0, 0};
  for (int i = idx; i < nh4; i += nthr)
    h4[nh4 + i] = uint4{0x00010001u, 0x00010001u, 0x00010001u, 0x00010001u};
  const float4* x4 = (const float4*)x;
  ushort4* xo = (ushort4*)xbf;
  const int n4 = NB * NS * ND / 4;
  for (int i = idx; i < n4; i += nthr) {
    float4 v = x4[i];
    ushort4 o;
    o.x = f2bf(v.x); o.y = f2bf(v.y); o.z = f2bf(v.z); o.w = f2bf(v.w);
    xo[i] = o;
  }
}

// ---------------- main persistent kernel (r7 minus flag protocol) ----------------
// h exchange is self-validating: even-column bf16 halfwords carry step-parity
// in bit0. Consumer poll == the data load; no flags, no drains, 3 barriers/step
// (B_C re-added: orders waves 4-7's x staging vs next step's P2 reads).
__global__ __launch_bounds__(NTHR)
void lstm_kernel(const float* __restrict__ Wih,
                 const float* __restrict__ Whh,
                 const float* __restrict__ bias,
                 const unsigned short* __restrict__ xbf,
                 unsigned short* __restrict__ hbuf,   // 2 ping-pong NB*NH bf16 (LLC)
                 float* __restrict__ out)
{
  const int tid  = threadIdx.x;
  const int wg   = blockIdx.x;
  const int wave = tid >> 6;
  const int lane = tid & 63;
  const int bb   = wg >> 6;       // batch block (hb-major: XCD-chunk locality)
  const int hb   = wg & 63;       // hidden block (16 cols)
  const int gp   = wave & 1;      // gate pair: 0 -> {i,f}, 1 -> {g,o}
  const int q    = wave >> 1;     // K quarter (x-ksteps 4q..4q+3, h-ksteps 8q..8q+7)

  __shared__ unsigned short tile[16 * 1536];  // [16][512 x | 1024 h] bf16, swizzled
  __shared__ float part[16][16 * PS];
  __shared__ float c_state[256];

  if (tid < 256) c_state[tid] = 0.0f;

  // ---------- one-time weight B-frag gather (col = lane&15, k = kbase+(lane>>4)*8+j) ----
  const int kg0  = (lane >> 4) << 3;
  const int colb = (hb << 4) + (lane & 15);
  bf16x8 wx[2][4], wh[2][8];
#pragma unroll
  for (int gg = 0; gg < 2; ++gg) {
    const int col = ((gp * 2 + gg) << 10) + colb;
#pragma unroll
    for (int s = 0; s < 4; ++s) {
      const int k0 = (q * 4 + s) * 32 + kg0;
#pragma unroll
      for (int j = 0; j < 8; ++j)
        wx[gg][s][j] = (short)f2bf(Wih[(size_t)(k0 + j) * G4H + col]);
    }
#pragma unroll
    for (int u = 0; u < 8; ++u) {
      const int k0 = (q * 8 + u) * 32 + kg0;
#pragma unroll
      for (int j = 0; j < 8; ++j)
        wh[gg][u][j] = (short)f2bf(Whh[(size_t)(k0 + j) * G4H + col]);
    }
  }

  // ---------- prologue: stage x(0); zero h region ----------
  for (int c = tid; c < 1024; c += NTHR) {       // 16 rows x 64 slots(16B) of x
    const int row = c >> 6, sl = c & 63;
    const unsigned short* src = xbf + (size_t)(bb * 16 + row) * (NS * ND) + sl * 8;
    *(uint4*)((char*)tile + swz(row, sl * 16)) = *(const uint4*)src;
  }
  for (int c = tid; c < 2048; c += NTHR) {       // 16 rows x 128 slots of h
    const int row = c >> 7, sl = c & 127;
    *(uint4*)((char*)tile + swz(row, 1024 + sl * 16)) = uint4{0, 0, 0, 0};
  }
  __syncthreads();

  const int arow = lane & 15;
  float* ht_out = out + (size_t)NB * NS * NH;
  float* ct_out = ht_out + NB * NH;

  for (int t = 0; t < NS; ++t) {
    // ---- P1: issue initial h(t) loads (4 x 16B per thread) ----
    constexpr unsigned long long M = 0x0000000100000001ull;
    const unsigned long long T = ((t >> 1) & 1) ? M : 0ull;
    unsigned long long hq0[4], hq1[4];
    const unsigned long long* hp[4];
    if (t > 0) {
      const unsigned short* hbase = hbuf + (size_t)(t & 1) * (NB * NH);
#pragma unroll
      for (int u = 0; u < 4; ++u) {
        const int row = 2 * wave + (u >> 1);
        const int sl  = (u & 1) * 64 + lane;
        hp[u] = (const unsigned long long*)(hbase + (size_t)(bb * 16 + row) * NH + sl * 8);
        hq0[u] = __hip_atomic_load(hp[u],     __ATOMIC_RELAXED, __HIP_MEMORY_SCOPE_AGENT);
        hq1[u] = __hip_atomic_load(hp[u] + 1, __ATOMIC_RELAXED, __HIP_MEMORY_SCOPE_AGENT);
      }
    }

    // ---- P2: x-part MFMAs (hide initial h-load latency) ----
    f32x4 a0 = {0.f, 0.f, 0.f, 0.f}, a1 = {0.f, 0.f, 0.f, 0.f};
#pragma unroll
    for (int s = 0; s < 4; ++s) {
      const int off = ((q * 4 + s) * 32 + kg0) * 2;
      bf16x8 af = *(const bf16x8*)((const char*)tile + swz(arow, off));
      a0 = __builtin_amdgcn_mfma_f32_16x16x32_bf16(af, wx[0][s], a0, 0, 0, 0);
      a1 = __builtin_amdgcn_mfma_f32_16x16x32_bf16(af, wx[1][s], a1, 0, 0, 0);
    }

    // ---- P3: validate tags (poll = reload stale chunks) + ds_write h slice ----
    if (t > 0) {
      while (true) {
        int stale = 0;
#pragma unroll
        for (int u = 0; u < 4; ++u)
          if ((((hq0[u] ^ T) | (hq1[u] ^ T)) & M) != 0ull) stale |= (1 << u);
        if (__all(stale == 0)) break;
#pragma unroll
        for (int u = 0; u < 4; ++u)
          if (stale & (1 << u)) {
            hq0[u] = __hip_atomic_load(hp[u],     __ATOMIC_RELAXED, __HIP_MEMORY_SCOPE_AGENT);
            hq1[u] = __hip_atomic_load(hp[u] + 1, __ATOMIC_RELAXED, __HIP_MEMORY_SCOPE_AGENT);
          }
      }
#pragma unroll
      for (int u = 0; u < 4; ++u) {
        const int row = 2 * wave + (u >> 1);
        const int sl  = (u & 1) * 64 + lane;
        uint4 v;
        v.x = (unsigned int)hq0[u];
        v.y = (unsigned int)(hq0[u] >> 32);
        v.z = (unsigned int)hq1[u];
        v.w = (unsigned int)(hq1[u] >> 32);
        *(uint4*)((char*)tile + swz(row, 1024 + sl * 16)) = v;
      }
    }
    __syncthreads();  // B_A: h region ready

    // ---- P5: h-part MFMAs ----
#pragma unroll
    for (int u = 0; u < 8; ++u) {
      const int off = 1024 + ((q * 8 + u) * 32 + kg0) * 2;
      bf16x8 af = *(const bf16x8*)((const char*)tile + swz(arow, off));
      a0 = __builtin_amdgcn_mfma_f32_16x16x32_bf16(af, wh[0][u], a0, 0, 0, 0);
      a1 = __builtin_amdgcn_mfma_f32_16x16x32_bf16(af, wh[1][u], a1, 0, 0, 0);
    }

    // ---- P6: partial tiles (C/D: col = lane&15, row = (lane>>4)*4 + reg) ----
    {
      const int r0 = (lane >> 4) << 2;
      const int cc = lane & 15;
#pragma unroll
      for (int j = 0; j < 4; ++j) {
        part[wave * 2 + 0][(r0 + j) * PS + cc] = a0[j];
        part[wave * 2 + 1][(r0 + j) * PS + cc] = a1[j];
      }
    }
    __syncthreads();  // B_B: parts ready, tile-x free

    // ---- P7: epilogue (waves 0-3) || x(t+1) staging (waves 4-7) ----
    if (tid < 256) {
      const int ec = tid & 15;
      const int er = tid >> 4;
      float pre[4];
#pragma unroll
      for (int go = 0; go < 4; ++go) {
        float s = bias[(go << 10) + (hb << 4) + ec];
#pragma unroll
        for (int qq = 0; qq < 4; ++qq)
          s += part[(qq * 2 + (go >> 1)) * 2 + (go & 1)][er * PS + ec];
        pre[go] = s;
      }
      const float it = sigmoidf_fast(pre[0]);
      const float ft = sigmoidf_fast(pre[1]);
      const float gt = tanhf_fast(pre[2]);
      const float ot = sigmoidf_fast(pre[3]);
      const float cn = ft * c_state[tid] + it * gt;
      c_state[tid] = cn;
      const float hn = ot * tanhf_fast(cn);
      const int row  = bb * 16 + er;
      const int hcol = (hb << 4) + ec;
      const size_t ooff = (size_t)row * (NS * NH) + (size_t)t * NH + hcol;
      if (t == NS - 1) {
        out[ooff] = hn;
        ht_out[row * NH + hcol] = hn;
        ct_out[row * NH + hcol] = cn;
      } else {
        // tagged bf16 pair -> one fire-and-forget sc1 store (no drain, no flag)
        const unsigned int tagw = (unsigned int)(((t + 1) >> 1) & 1);
        unsigned int my  = (unsigned int)f2bf(hn);
        unsigned int pa  = (unsigned int)__shfl_xor((int)my, 1, 64);  // odd col, untagged
        if ((tid & 1) == 0) {
          unsigned int myt = (my & ~1u) | tagw;   // even col carries the tag bit
          unsigned int* p = (unsigned int*)(hbuf + (size_t)((t + 1) & 1) * (NB * NH)
                                                 + (size_t)row * NH + hcol);
          __hip_atomic_store(p, myt | (pa << 16), __ATOMIC_RELAXED, __HIP_MEMORY_SCOPE_AGENT);
        }
        __builtin_nontemporal_store(hn, &out[ooff]);
      }
    } else if (t < NS - 1) {
      // x(t+1): 1024 chunks of 16B over 256 threads
      for (int c = tid - 256; c < 1024; c += 256) {
        const int row = c >> 6, sl = c & 63;
        const unsigned short* src = xbf + (size_t)(bb * 16 + row) * (NS * ND)
                                        + (size_t)(t + 1) * ND + sl * 8;
        *(uint4*)((char*)tile + swz(row, sl * 16)) = *(const uint4*)src;
      }
    }
    if (t < NS - 1) __syncthreads();  // B_C: x staged before next P2 reads it
  }
}

extern "C" void kernel_launch(void* const* d_in, const int* in_sizes, int n_in,
                              void* d_out, int out_size, void* d_ws, size_t ws_size,
                              hipStream_t stream) {
  const float* x    = (const float*)d_in[0];
  const float* wih  = (const float*)d_in[1];
  const float* whh  = (const float*)d_in[2];
  const float* bias = (const float*)d_in[3];
  float* out = (float*)d_out;

  // ws layout: [hbuf 2*NB*NH bf16 = 256KB][xbf NB*NS*ND bf16 = 32MB]
  unsigned short* hbuf = (unsigned short*)d_ws;
  unsigned short* xbf  = (unsigned short*)((char*)d_ws + (size_t)2 * NB * NH * 2);

  prep_kernel<<<1024, 256, 0, stream>>>(x, xbf, hbuf);

  void* args[] = { (void*)&wih, (void*)&whh, (void*)&bias,
                   (void*)&xbf, (void*)&hbuf, (void*)&out };
  hipLaunchCooperativeKernel((const void*)lstm_kernel, dim3(NWG), dim3(NTHR),
                             args, 0, stream);
}